// Round 4
// baseline (128.021 us; speedup 1.0000x reference)
//
#include <hip/hip_runtime.h>
#include <hip/hip_bf16.h>
#include <math.h>

#define B 2
#define N 1024
#define D 128
#define DA 32
#define NH 4
#define AH 32
#define DEC_H 256
#define DEC_O 128
#define C_DIM ((NH + 1) * D)   // 640
#define TI 32
#define TJ 32
#define SPLIT 4                // j-dimension split for occupancy
#define JCHUNK (N / SPLIT)     // 256

typedef __attribute__((ext_vector_type(8))) short bf16x8;
typedef __attribute__((ext_vector_type(4))) float f32x4;

// round-to-nearest-even f32 -> bf16 (no NaN handling needed for our data)
static __device__ __forceinline__ unsigned pack2bf(float a, float b) {
    unsigned ua = __float_as_uint(a), ub = __float_as_uint(b);
    unsigned ra = (ua + 0x7FFFu + ((ua >> 16) & 1u)) >> 16;
    unsigned rb = (ub + 0x7FFFu + ((ub >> 16) & 1u)) >> 16;
    return (ra & 0xFFFFu) | (rb << 16);
}

// ---------------- kernel 1: k, q, v projections ----------------
// grid B*N/4 = 512 blocks x 384 threads; 4 rows per block.
__global__ __launch_bounds__(384) void qkv_kernel(
    const float* __restrict__ x,
    const float* __restrict__ Wk, const float* __restrict__ bk,
    const float* __restrict__ Wq, const float* __restrict__ bq,
    const float* __restrict__ Wv, const float* __restrict__ bv,
    float* __restrict__ kOut, float* __restrict__ qOut, float* __restrict__ cBuf)
{
    const int t = threadIdx.x;
    const int row0 = blockIdx.x * 4;
    __shared__ float xs[4][D];
    for (int idx = t; idx < 4 * D; idx += 384)
        xs[idx >> 7][idx & 127] = x[(size_t)row0 * D + idx];
    __syncthreads();

    const int mat = t >> 7;      // 0,1,2 (wave-uniform)
    const int col = t & 127;
    const float* W = (mat == 0) ? Wk : (mat == 1) ? Wq : Wv;
    const float bias = (mat == 0) ? bk[col] : (mat == 1) ? bq[col] : bv[col];

    float a[4];
    #pragma unroll
    for (int m = 0; m < 4; ++m) a[m] = bias;
    for (int d = 0; d < D; ++d) {
        const float w = W[d * D + col];
        #pragma unroll
        for (int m = 0; m < 4; ++m) a[m] = fmaf(xs[m][d], w, a[m]);
    }
    if (mat == 0) {
        #pragma unroll
        for (int m = 0; m < 4; ++m) kOut[(size_t)(row0 + m) * D + col] = a[m];
    } else if (mat == 1) {
        #pragma unroll
        for (int m = 0; m < 4; ++m) qOut[(size_t)(row0 + m) * D + col] = a[m];
    } else {
        #pragma unroll
        for (int m = 0; m < 4; ++m) cBuf[(size_t)(row0 + m) * C_DIM + col] = a[m];
    }
}

// ---------------- kernel 2: hk = ki@Wa1_k ; hq = qi@Wa1_q + ba1 ----------------
__global__ __launch_bounds__(256) void hkq_kernel(
    const float* __restrict__ kIn, const float* __restrict__ qIn,
    const float* __restrict__ Wa1, const float* __restrict__ ba1,
    float* __restrict__ hkOut, float* __restrict__ hqOut)
{
    const int row = blockIdx.x;   // b*N + n
    const int t = threadIdx.x;    // 0..255
    __shared__ float ks[D], qs[D];
    if (t < D) ks[t] = kIn[(size_t)row * D + t];
    else       qs[t - D] = qIn[(size_t)row * D + (t - D)];
    __syncthreads();

    const bool isq = t >= 128;
    const int tt = t & 127;
    const int head = tt >> 5;   // 0..3
    const int a = tt & 31;      // 0..31
    const float* src = isq ? qs : ks;
    const float* W = Wa1 + (isq ? DA * AH : 0);
    float acc = isq ? ba1[a] : 0.f;
    #pragma unroll
    for (int c = 0; c < DA; ++c)
        acc = fmaf(src[head * DA + c], W[c * AH + a], acc);

    const int b = row >> 10, n = row & (N - 1);
    float* dst = isq ? hqOut : hkOut;
    dst[(((size_t)(b * NH + head)) * N + n) * 32 + a] = acc;
}

// ---------------- kernel 3: attention (j-split partials, bf16 MFMA PV) ----------------
// grid = B*NH*(N/TI)*SPLIT = 1024 blocks x 256 threads.
// Scores 32x32 on VALU (f32), sigmoid -> bf16 into wbf[i][j] (A-operand layout).
// v staged transposed bf16 vtbf[d][j] (B-operand [n][k] layout).
// PV via 4x mfma_f32_16x16x32_bf16 per wave per j-tile.
__global__ __launch_bounds__(256, 4) void attn_kernel(
    const float* __restrict__ hk, const float* __restrict__ hq,
    const float* __restrict__ Wa2, const float* __restrict__ ba2,
    const float* __restrict__ cBuf, float* __restrict__ pBuf)
{
    const int t = threadIdx.x;
    const int sc = blockIdx.x & (SPLIT - 1);
    const int tile = (blockIdx.x >> 2) & 31;
    const int bh = blockIdx.x >> 7;     // b*NH + h
    const int b = bh >> 2;
    const int i0 = tile * TI;

    __shared__ float hks[TI][36];
    __shared__ float hqs[TJ][36];
    __shared__ unsigned wbf[TI][20];     // bf16 w[i][j]: 16 u32 (32 j) + 4 pad; 80B rows
    __shared__ unsigned vtbf[D][20];     // bf16 vT[d][j]: same row layout

    // wa2 cached in registers (static indexing)
    float4 wa2r[8];
    #pragma unroll
    for (int a4 = 0; a4 < 8; ++a4) wa2r[a4] = reinterpret_cast<const float4*>(Wa2)[a4];
    const float ba2v = ba2[0];

    {   // load hk tile (32x32), resident across whole j-loop
        const float* src = hk + ((size_t)bh * N + i0) * 32;
        for (int idx = t; idx < TI * 32; idx += 256)
            hks[idx >> 5][idx & 31] = src[idx];
    }

    // score-thread mapping (2x2 scores per thread)
    const int ti2 = (t >> 4) << 1;       // score rows: ti2, ti2+1
    const int tj2 = (t & 15) << 1;       // score cols: tj2, tj2+1
    // mfma mapping
    const int lane = t & 63;
    const int wv = t >> 6;               // wave id: d-tiles {2wv, 2wv+1}
    const int lm = lane & 15;
    const int lg = lane >> 4;

    f32x4 acc00 = {0.f, 0.f, 0.f, 0.f};
    f32x4 acc01 = {0.f, 0.f, 0.f, 0.f};
    f32x4 acc10 = {0.f, 0.f, 0.f, 0.f};
    f32x4 acc11 = {0.f, 0.f, 0.f, 0.f};

    const int jbeg = sc * JCHUNK, jend = jbeg + JCHUNK;
    for (int j0 = jbeg; j0 < jend; j0 += TJ) {
        __syncthreads();   // previous iteration's score reads + mfma reads done
        {   // stage hq tile (f32)
            const float* src = hq + ((size_t)bh * N + j0) * 32;
            for (int idx = t; idx < TJ * 32; idx += 256)
                hqs[idx >> 5][idx & 31] = src[idx];
        }
        {   // stage v transposed -> bf16 (jp-minor: conflict-free LDS writes)
            const float* vsrc = cBuf + (size_t)(b * N + j0) * C_DIM;
            #pragma unroll
            for (int e = t; e < 2048; e += 256) {       // 8 iters
                const int jp = e & 15, d = e >> 4;
                const float v0 = vsrc[(size_t)(2 * jp) * C_DIM + d];
                const float v1 = vsrc[(size_t)(2 * jp + 1) * C_DIM + d];
                vtbf[d][jp] = pack2bf(v0, v1);
            }
        }
        __syncthreads();

        {   // scores: 2x2 per thread, f32
            float s00 = ba2v, s01 = ba2v, s10 = ba2v, s11 = ba2v;
            #pragma unroll
            for (int a4 = 0; a4 < 8; ++a4) {
                const float4 k0 = *reinterpret_cast<const float4*>(&hks[ti2][a4 * 4]);
                const float4 k1 = *reinterpret_cast<const float4*>(&hks[ti2 + 1][a4 * 4]);
                const float4 q0 = *reinterpret_cast<const float4*>(&hqs[tj2][a4 * 4]);
                const float4 q1 = *reinterpret_cast<const float4*>(&hqs[tj2 + 1][a4 * 4]);
                const float4 w4 = wa2r[a4];
                s00 += w4.x * fmaxf(k0.x + q0.x, 0.f) + w4.y * fmaxf(k0.y + q0.y, 0.f)
                     + w4.z * fmaxf(k0.z + q0.z, 0.f) + w4.w * fmaxf(k0.w + q0.w, 0.f);
                s01 += w4.x * fmaxf(k0.x + q1.x, 0.f) + w4.y * fmaxf(k0.y + q1.y, 0.f)
                     + w4.z * fmaxf(k0.z + q1.z, 0.f) + w4.w * fmaxf(k0.w + q1.w, 0.f);
                s10 += w4.x * fmaxf(k1.x + q0.x, 0.f) + w4.y * fmaxf(k1.y + q0.y, 0.f)
                     + w4.z * fmaxf(k1.z + q0.z, 0.f) + w4.w * fmaxf(k1.w + q0.w, 0.f);
                s11 += w4.x * fmaxf(k1.x + q1.x, 0.f) + w4.y * fmaxf(k1.y + q1.y, 0.f)
                     + w4.z * fmaxf(k1.z + q1.z, 0.f) + w4.w * fmaxf(k1.w + q1.w, 0.f);
            }
            const int gi0 = i0 + ti2, gj0 = j0 + tj2;
            if (gi0 == gj0)     { s00 -= 10000.f; s11 -= 10000.f; }
            if (gi0 == gj0 + 1) { s01 -= 10000.f; }
            if (gi0 + 1 == gj0) { s10 -= 10000.f; }
            const float w00 = 1.f / (1.f + __expf(-s00));
            const float w01 = 1.f / (1.f + __expf(-s01));
            const float w10 = 1.f / (1.f + __expf(-s10));
            const float w11 = 1.f / (1.f + __expf(-s11));
            wbf[ti2][t & 15]     = pack2bf(w00, w01);   // row ti2,  cols (tj2, tj2+1)
            wbf[ti2 + 1][t & 15] = pack2bf(w10, w11);
        }
        __syncthreads();

        {   // PV: D[i][d] += w[i][j] * v[j][d] via mfma (K = 32 = full j-tile)
            const char* wbase = reinterpret_cast<const char*>(&wbf[0][0]);
            const char* vbase = reinterpret_cast<const char*>(&vtbf[0][0]);
            const bf16x8 a0 = *reinterpret_cast<const bf16x8*>(wbase + lm * 80 + lg * 16);
            const bf16x8 a1 = *reinterpret_cast<const bf16x8*>(wbase + (16 + lm) * 80 + lg * 16);
            const bf16x8 b0 = *reinterpret_cast<const bf16x8*>(vbase + ((2 * wv) * 16 + lm) * 80 + lg * 16);
            const bf16x8 b1 = *reinterpret_cast<const bf16x8*>(vbase + ((2 * wv + 1) * 16 + lm) * 80 + lg * 16);
            acc00 = __builtin_amdgcn_mfma_f32_16x16x32_bf16(a0, b0, acc00, 0, 0, 0);
            acc01 = __builtin_amdgcn_mfma_f32_16x16x32_bf16(a0, b1, acc01, 0, 0, 0);
            acc10 = __builtin_amdgcn_mfma_f32_16x16x32_bf16(a1, b0, acc10, 0, 0, 0);
            acc11 = __builtin_amdgcn_mfma_f32_16x16x32_bf16(a1, b1, acc11, 0, 0, 0);
        }
    }

    // write 32x128 partial tile to pBuf[blockIdx.x] (D-frag: col=lane&15, row=4*lg+r)
    float* dst = pBuf + (size_t)blockIdx.x * (TI * D);
    #pragma unroll
    for (int r = 0; r < 4; ++r) {
        const int ia = lg * 4 + r;
        dst[ia * D + (2 * wv) * 16 + lm]            = acc00[r];
        dst[ia * D + (2 * wv + 1) * 16 + lm]        = acc01[r];
        dst[(16 + ia) * D + (2 * wv) * 16 + lm]     = acc10[r];
        dst[(16 + ia) * D + (2 * wv + 1) * 16 + lm] = acc11[r];
    }
}

// ---------------- kernel 3b: reduce SPLIT partials into cBuf ----------------
__global__ __launch_bounds__(256) void reduce_kernel(
    const float* __restrict__ pBuf, float* __restrict__ cBuf)
{
    const int e4 = blockIdx.x * 256 + threadIdx.x;   // 0 .. 262143
    const int d4 = e4 & 31;
    const int i = (e4 >> 5) & 31;
    const int tile = (e4 >> 10) & 31;
    const int bh = e4 >> 15;
    const float4* p = reinterpret_cast<const float4*>(pBuf);
    const size_t base = ((size_t)(bh * 32 + tile) * SPLIT) * (TI * D / 4) + i * (D / 4) + d4;
    float4 s = p[base];
    #pragma unroll
    for (int sc = 1; sc < SPLIT; ++sc) {
        const float4 q = p[base + (size_t)sc * (TI * D / 4)];
        s.x += q.x; s.y += q.y; s.z += q.z; s.w += q.w;
    }
    const int b = bh >> 2, h = bh & 3;
    reinterpret_cast<float4*>(cBuf + (size_t)(b * N + tile * 32 + i) * C_DIM + (h + 1) * D)[d4] = s;
}

// ---------------- kernel 4: decoder ----------------
__global__ __launch_bounds__(512) void dec_kernel(
    const float* __restrict__ cBuf,
    const float* __restrict__ Wd1, const float* __restrict__ bd1,
    const float* __restrict__ Wd2, const float* __restrict__ bd2,
    float* __restrict__ out)
{
    const int t = threadIdx.x;       // 0..511
    const int r0 = blockIdx.x * 8;
    __shared__ float cs[8][C_DIM];
    __shared__ float hs[8][DEC_H];

    {   // load 8 rows of c (8*640 floats = 1280 float4)
        const float4* src = reinterpret_cast<const float4*>(cBuf + (size_t)r0 * C_DIM);
        float4* dst4 = reinterpret_cast<float4*>(&cs[0][0]);
        for (int idx = t; idx < 8 * C_DIM / 4; idx += 512) dst4[idx] = src[idx];
    }
    __syncthreads();

    // layer 1: col = t&255, rows (t>>8)*4 .. +3
    {
        const int col = t & 255, rh = t >> 8;
        float hacc[4];
        const float b1 = bd1[col];
        #pragma unroll
        for (int m = 0; m < 4; ++m) hacc[m] = b1;
        for (int d = 0; d < C_DIM; ++d) {
            const float w = Wd1[(size_t)d * DEC_H + col];
            #pragma unroll
            for (int m = 0; m < 4; ++m) hacc[m] = fmaf(cs[rh * 4 + m][d], w, hacc[m]);
        }
        #pragma unroll
        for (int m = 0; m < 4; ++m) hs[rh * 4 + m][col] = fmaxf(hacc[m], 0.f);
    }
    __syncthreads();

    // layer 2: col o = t&127, rows (t>>7)*2 .. +1
    {
        const int o = t & 127, rq = t >> 7;
        float oacc[2];
        const float b2 = bd2[o];
        #pragma unroll
        for (int m = 0; m < 2; ++m) oacc[m] = b2;
        for (int hh = 0; hh < DEC_H; ++hh) {
            const float w = Wd2[(size_t)hh * DEC_O + o];
            #pragma unroll
            for (int m = 0; m < 2; ++m) oacc[m] = fmaf(hs[rq * 2 + m][hh], w, oacc[m]);
        }
        #pragma unroll
        for (int m = 0; m < 2; ++m)
            out[(size_t)(r0 + rq * 2 + m) * DEC_O + o] = oacc[m];
    }
}

extern "C" void kernel_launch(void* const* d_in, const int* in_sizes, int n_in,
                              void* d_out, int out_size, void* d_ws, size_t ws_size,
                              hipStream_t stream)
{
    const float* x   = (const float*)d_in[0];
    const float* Wk  = (const float*)d_in[1];
    const float* bk  = (const float*)d_in[2];
    const float* Wq  = (const float*)d_in[3];
    const float* bq  = (const float*)d_in[4];
    const float* Wv  = (const float*)d_in[5];
    const float* bv  = (const float*)d_in[6];
    const float* Wa1 = (const float*)d_in[7];
    const float* ba1 = (const float*)d_in[8];
    const float* Wa2 = (const float*)d_in[9];
    const float* ba2 = (const float*)d_in[10];
    const float* Wd1 = (const float*)d_in[11];
    const float* bd1 = (const float*)d_in[12];
    const float* Wd2 = (const float*)d_in[13];
    const float* bd2 = (const float*)d_in[14];
    float* out = (float*)d_out;

    float* ws = (float*)d_ws;
    float* kBuf  = ws;                                   // B*N*D
    float* qBuf  = kBuf + (size_t)B * N * D;             // B*N*D
    float* hkBuf = qBuf + (size_t)B * N * D;             // B*NH*N*32
    float* hqBuf = hkBuf + (size_t)B * NH * N * 32;      // B*NH*N*32
    float* cBuf  = hqBuf + (size_t)B * NH * N * 32;      // B*N*C_DIM
    float* pBuf  = cBuf + (size_t)B * N * C_DIM;         // 1024*32*128 floats

    qkv_kernel<<<B * N / 4, 384, 0, stream>>>(x, Wk, bk, Wq, bq, Wv, bv, kBuf, qBuf, cBuf);
    hkq_kernel<<<B * N, 256, 0, stream>>>(kBuf, qBuf, Wa1, ba1, hkBuf, hqBuf);
    attn_kernel<<<B * NH * (N / TI) * SPLIT, 256, 0, stream>>>(hkBuf, hqBuf, Wa2, ba2, cBuf, pBuf);
    reduce_kernel<<<B * NH * (N / TI) * TI * D / 4 / 256, 256, 0, stream>>>(pBuf, cBuf);
    dec_kernel<<<B * N / 8, 512, 0, stream>>>(cBuf, Wd1, bd1, Wd2, bd2, out);
}

// Round 5
// 94.631 us; speedup vs baseline: 1.3529x; 1.3529x over previous
//
#include <hip/hip_runtime.h>
#include <hip/hip_bf16.h>
#include <math.h>

#define B 2
#define N 1024
#define D 128
#define DA 32
#define NH 4
#define AH 32
#define DEC_H 256
#define DEC_O 128
#define C_DIM ((NH + 1) * D)   // 640
#define TI 32
#define TJ 32
#define SPLIT 4                // j-dimension split for occupancy
#define JCHUNK (N / SPLIT)     // 256

typedef __attribute__((ext_vector_type(8))) short bf16x8;
typedef __attribute__((ext_vector_type(4))) float f32x4;
typedef __attribute__((ext_vector_type(4))) unsigned u32x4;

// round-to-nearest-even f32 -> bf16
static __device__ __forceinline__ unsigned pack2bf(float a, float b) {
    unsigned ua = __float_as_uint(a), ub = __float_as_uint(b);
    unsigned ra = (ua + 0x7FFFu + ((ua >> 16) & 1u)) >> 16;
    unsigned rb = (ub + 0x7FFFu + ((ub >> 16) & 1u)) >> 16;
    return (ra & 0xFFFFu) | (rb << 16);
}
static __device__ __forceinline__ unsigned short tobf(float a) {
    unsigned ua = __float_as_uint(a);
    return (unsigned short)((ua + 0x7FFFu + ((ua >> 16) & 1u)) >> 16);
}

// ---------------- kernel 1: k, q, v projections ----------------
__global__ __launch_bounds__(384) void qkv_kernel(
    const float* __restrict__ x,
    const float* __restrict__ Wk, const float* __restrict__ bk,
    const float* __restrict__ Wq, const float* __restrict__ bq,
    const float* __restrict__ Wv, const float* __restrict__ bv,
    float* __restrict__ kOut, float* __restrict__ qOut, float* __restrict__ cBuf)
{
    const int t = threadIdx.x;
    const int row0 = blockIdx.x * 4;
    __shared__ float xs[4][D];
    for (int idx = t; idx < 4 * D; idx += 384)
        xs[idx >> 7][idx & 127] = x[(size_t)row0 * D + idx];
    __syncthreads();

    const int mat = t >> 7;      // 0,1,2 (wave-uniform)
    const int col = t & 127;
    const float* W = (mat == 0) ? Wk : (mat == 1) ? Wq : Wv;
    const float bias = (mat == 0) ? bk[col] : (mat == 1) ? bq[col] : bv[col];

    float a[4];
    #pragma unroll
    for (int m = 0; m < 4; ++m) a[m] = bias;
    for (int d = 0; d < D; ++d) {
        const float w = W[d * D + col];
        #pragma unroll
        for (int m = 0; m < 4; ++m) a[m] = fmaf(xs[m][d], w, a[m]);
    }
    if (mat == 0) {
        #pragma unroll
        for (int m = 0; m < 4; ++m) kOut[(size_t)(row0 + m) * D + col] = a[m];
    } else if (mat == 1) {
        #pragma unroll
        for (int m = 0; m < 4; ++m) qOut[(size_t)(row0 + m) * D + col] = a[m];
    } else {
        #pragma unroll
        for (int m = 0; m < 4; ++m) cBuf[(size_t)(row0 + m) * C_DIM + col] = a[m];
    }
}

// ---------------- kernel 2: hk = ki@Wa1_k ; hq = qi@Wa1_q + ba1 ----------------
__global__ __launch_bounds__(256) void hkq_kernel(
    const float* __restrict__ kIn, const float* __restrict__ qIn,
    const float* __restrict__ Wa1, const float* __restrict__ ba1,
    float* __restrict__ hkOut, float* __restrict__ hqOut)
{
    const int row = blockIdx.x;   // b*N + n
    const int t = threadIdx.x;    // 0..255
    __shared__ float ks[D], qs[D];
    if (t < D) ks[t] = kIn[(size_t)row * D + t];
    else       qs[t - D] = qIn[(size_t)row * D + (t - D)];
    __syncthreads();

    const bool isq = t >= 128;
    const int tt = t & 127;
    const int head = tt >> 5;   // 0..3
    const int a = tt & 31;      // 0..31
    const float* src = isq ? qs : ks;
    const float* W = Wa1 + (isq ? DA * AH : 0);
    float acc = isq ? ba1[a] : 0.f;
    #pragma unroll
    for (int c = 0; c < DA; ++c)
        acc = fmaf(src[head * DA + c], W[c * AH + a], acc);

    const int b = row >> 10, n = row & (N - 1);
    float* dst = isq ? hqOut : hkOut;
    dst[(((size_t)(b * NH + head)) * N + n) * 32 + a] = acc;
}

// ---------------- kernel 3: attention ----------------
// grid = B*NH*(N/TI)*SPLIT = 1024 blocks x 256 threads.
// hk rows register-resident (block-invariant). hq staged in LDS (2-way-max
// conflict mapping). Scores 2i x 2j per thread, cols (j, j+16). Sigmoid ->
// bf16 u16 stores into wbf (A-operand layout). V fragments loaded directly
// global->regs in B-operand layout (coalesced 4-line loads), packed to bf16.
// PV via 4x mfma_f32_16x16x32_bf16 per wave. Two barriers per iteration:
//   [stage hqs; issue v-loads; SYNC_A; scores->wbf; pack v; SYNC_B; mfma]
// hqs-read(n) < SYNC_B(n) < hqs-write(n+1); wbf-read(n) < SYNC_A(n+1) < wbf-write(n+1).
__global__ __launch_bounds__(256, 4) void attn_kernel(
    const float* __restrict__ hk, const float* __restrict__ hq,
    const float* __restrict__ Wa2, const float* __restrict__ ba2,
    const float* __restrict__ cBuf, float* __restrict__ pBuf)
{
    const int t = threadIdx.x;
    const int sc = blockIdx.x & (SPLIT - 1);
    const int tile = (blockIdx.x >> 2) & 31;
    const int bh = blockIdx.x >> 7;     // b*NH + h
    const int b = bh >> 2;
    const int i0 = tile * TI;

    __shared__ float hqs[TJ][36];        // 144B rows (16B aligned)
    __shared__ unsigned wbf[TI][20];     // bf16 w[i][j]: 80B rows

    const float ba2v = ba2[0];

    // score mapping: rows (ti2, ti2+1), cols (tjA, tjA+16)
    const int ti2 = (t >> 4) << 1;
    const int tjA = t & 15;

    // hk rows in registers (block-invariant across the j-loop)
    float4 hkr0[8], hkr1[8];
    {
        const float4* s0 = reinterpret_cast<const float4*>(hk + ((size_t)bh * N + i0 + ti2) * 32);
        const float4* s1 = reinterpret_cast<const float4*>(hk + ((size_t)bh * N + i0 + ti2 + 1) * 32);
        #pragma unroll
        for (int a4 = 0; a4 < 8; ++a4) { hkr0[a4] = s0[a4]; hkr1[a4] = s1[a4]; }
    }

    // mfma mapping
    const int lane = t & 63;
    const int wv = t >> 6;               // wave id: d-tiles {2wv, 2wv+1}
    const int lm = lane & 15;
    const int lg = lane >> 4;

    f32x4 acc00 = {0.f, 0.f, 0.f, 0.f};
    f32x4 acc01 = {0.f, 0.f, 0.f, 0.f};
    f32x4 acc10 = {0.f, 0.f, 0.f, 0.f};
    f32x4 acc11 = {0.f, 0.f, 0.f, 0.f};

    const int d0 = (2 * wv) * 16 + lm;   // B-frag columns
    const int d1 = d0 + 16;

    const int jbeg = sc * JCHUNK, jend = jbeg + JCHUNK;
    for (int j0 = jbeg; j0 < jend; j0 += TJ) {
        // stage hq tile (coalesced)
        {
            const float* src = hq + ((size_t)bh * N + j0) * 32;
            for (int idx = t; idx < TJ * 32; idx += 256)
                hqs[idx >> 5][idx & 31] = src[idx];
        }
        // issue v fragment loads (global, coalesced 4-line per instr)
        float v0[8], v1[8];
        {
            const float* vb = cBuf + (size_t)(b * N + j0 + 8 * lg) * C_DIM;
            #pragma unroll
            for (int e = 0; e < 8; ++e) {
                v0[e] = vb[(size_t)e * C_DIM + d0];
                v1[e] = vb[(size_t)e * C_DIM + d1];
            }
        }
        __syncthreads();   // SYNC_A: hqs ready; prev-iter wbf reads done

        {   // scores: 2x2 per thread (rows ti2/ti2+1, cols tjA/tjA+16)
            float sAA = ba2v, sAB = ba2v, sBA = ba2v, sBB = ba2v;
            #pragma unroll
            for (int a4 = 0; a4 < 8; ++a4) {
                const float4 qA = *reinterpret_cast<const float4*>(&hqs[tjA][a4 * 4]);
                const float4 qB = *reinterpret_cast<const float4*>(&hqs[tjA + 16][a4 * 4]);
                const float4 kA = hkr0[a4];
                const float4 kB = hkr1[a4];
                const float4 w4 = reinterpret_cast<const float4*>(Wa2)[a4];
                sAA += w4.x * fmaxf(kA.x + qA.x, 0.f) + w4.y * fmaxf(kA.y + qA.y, 0.f)
                     + w4.z * fmaxf(kA.z + qA.z, 0.f) + w4.w * fmaxf(kA.w + qA.w, 0.f);
                sAB += w4.x * fmaxf(kA.x + qB.x, 0.f) + w4.y * fmaxf(kA.y + qB.y, 0.f)
                     + w4.z * fmaxf(kA.z + qB.z, 0.f) + w4.w * fmaxf(kA.w + qB.w, 0.f);
                sBA += w4.x * fmaxf(kB.x + qA.x, 0.f) + w4.y * fmaxf(kB.y + qA.y, 0.f)
                     + w4.z * fmaxf(kB.z + qA.z, 0.f) + w4.w * fmaxf(kB.w + qA.w, 0.f);
                sBB += w4.x * fmaxf(kB.x + qB.x, 0.f) + w4.y * fmaxf(kB.y + qB.y, 0.f)
                     + w4.z * fmaxf(kB.z + qB.z, 0.f) + w4.w * fmaxf(kB.w + qB.w, 0.f);
            }
            const int giA = i0 + ti2, giB = giA + 1;
            const int gjA = j0 + tjA, gjB = gjA + 16;
            if (giA == gjA) sAA -= 10000.f;
            if (giA == gjB) sAB -= 10000.f;
            if (giB == gjA) sBA -= 10000.f;
            if (giB == gjB) sBB -= 10000.f;
            const float wAA = 1.f / (1.f + __expf(-sAA));
            const float wAB = 1.f / (1.f + __expf(-sAB));
            const float wBA = 1.f / (1.f + __expf(-sBA));
            const float wBB = 1.f / (1.f + __expf(-sBB));
            unsigned short* wb = reinterpret_cast<unsigned short*>(&wbf[0][0]);
            wb[ti2 * 40 + tjA]            = tobf(wAA);
            wb[ti2 * 40 + tjA + 16]       = tobf(wAB);
            wb[(ti2 + 1) * 40 + tjA]      = tobf(wBA);
            wb[(ti2 + 1) * 40 + tjA + 16] = tobf(wBB);
        }

        // pack v fragments to bf16 (waits on the early global loads)
        u32x4 pb0, pb1;
        pb0.x = pack2bf(v0[0], v0[1]); pb0.y = pack2bf(v0[2], v0[3]);
        pb0.z = pack2bf(v0[4], v0[5]); pb0.w = pack2bf(v0[6], v0[7]);
        pb1.x = pack2bf(v1[0], v1[1]); pb1.y = pack2bf(v1[2], v1[3]);
        pb1.z = pack2bf(v1[4], v1[5]); pb1.w = pack2bf(v1[6], v1[7]);
        const bf16x8 b0 = __builtin_bit_cast(bf16x8, pb0);
        const bf16x8 b1 = __builtin_bit_cast(bf16x8, pb1);

        __syncthreads();   // SYNC_B: wbf ready

        {   // PV: 4x mfma per wave
            const char* wbase = reinterpret_cast<const char*>(&wbf[0][0]);
            const bf16x8 a0 = *reinterpret_cast<const bf16x8*>(wbase + lm * 80 + lg * 16);
            const bf16x8 a1 = *reinterpret_cast<const bf16x8*>(wbase + (16 + lm) * 80 + lg * 16);
            acc00 = __builtin_amdgcn_mfma_f32_16x16x32_bf16(a0, b0, acc00, 0, 0, 0);
            acc01 = __builtin_amdgcn_mfma_f32_16x16x32_bf16(a0, b1, acc01, 0, 0, 0);
            acc10 = __builtin_amdgcn_mfma_f32_16x16x32_bf16(a1, b0, acc10, 0, 0, 0);
            acc11 = __builtin_amdgcn_mfma_f32_16x16x32_bf16(a1, b1, acc11, 0, 0, 0);
        }
    }

    // write 32x128 partial tile to pBuf[blockIdx.x] (D-frag: col=lane&15, row=4*lg+r)
    float* dst = pBuf + (size_t)blockIdx.x * (TI * D);
    #pragma unroll
    for (int r = 0; r < 4; ++r) {
        const int ia = lg * 4 + r;
        dst[ia * D + d0]        = acc00[r];
        dst[ia * D + d1]        = acc01[r];
        dst[(16 + ia) * D + d0] = acc10[r];
        dst[(16 + ia) * D + d1] = acc11[r];
    }
}

// ---------------- kernel 3b: reduce SPLIT partials into cBuf ----------------
__global__ __launch_bounds__(256) void reduce_kernel(
    const float* __restrict__ pBuf, float* __restrict__ cBuf)
{
    const int e4 = blockIdx.x * 256 + threadIdx.x;   // 0 .. 262143
    const int d4 = e4 & 31;
    const int i = (e4 >> 5) & 31;
    const int tile = (e4 >> 10) & 31;
    const int bh = e4 >> 15;
    const float4* p = reinterpret_cast<const float4*>(pBuf);
    const size_t base = ((size_t)(bh * 32 + tile) * SPLIT) * (TI * D / 4) + i * (D / 4) + d4;
    float4 s = p[base];
    #pragma unroll
    for (int sc = 1; sc < SPLIT; ++sc) {
        const float4 q = p[base + (size_t)sc * (TI * D / 4)];
        s.x += q.x; s.y += q.y; s.z += q.z; s.w += q.w;
    }
    const int b = bh >> 2, h = bh & 3;
    reinterpret_cast<float4*>(cBuf + (size_t)(b * N + tile * 32 + i) * C_DIM + (h + 1) * D)[d4] = s;
}

// ---------------- kernel 4: decoder ----------------
// grid B*N/4 = 512 blocks x 512 threads; 4 rows per block.
__global__ __launch_bounds__(512) void dec_kernel(
    const float* __restrict__ cBuf,
    const float* __restrict__ Wd1, const float* __restrict__ bd1,
    const float* __restrict__ Wd2, const float* __restrict__ bd2,
    float* __restrict__ out)
{
    const int t = threadIdx.x;       // 0..511
    const int r0 = blockIdx.x * 4;
    __shared__ float cs[4][C_DIM];
    __shared__ float hs[4][DEC_H];

    {   // load 4 rows of c (4*640 floats = 640 float4)
        const float4* src = reinterpret_cast<const float4*>(cBuf + (size_t)r0 * C_DIM);
        float4* dst4 = reinterpret_cast<float4*>(&cs[0][0]);
        for (int idx = t; idx < 4 * C_DIM / 4; idx += 512) dst4[idx] = src[idx];
    }
    __syncthreads();

    // layer 1: col = t&255, rows (t>>8)*2 .. +1
    {
        const int col = t & 255, rg = t >> 8;
        float hacc[2];
        const float b1 = bd1[col];
        #pragma unroll
        for (int m = 0; m < 2; ++m) hacc[m] = b1;
        for (int d = 0; d < C_DIM; ++d) {
            const float w = Wd1[(size_t)d * DEC_H + col];
            #pragma unroll
            for (int m = 0; m < 2; ++m) hacc[m] = fmaf(cs[rg * 2 + m][d], w, hacc[m]);
        }
        #pragma unroll
        for (int m = 0; m < 2; ++m) hs[rg * 2 + m][col] = fmaxf(hacc[m], 0.f);
    }
    __syncthreads();

    // layer 2: col o = t&127, row rq = t>>7
    {
        const int o = t & 127, rq = t >> 7;
        float oacc = bd2[o];
        for (int hh = 0; hh < DEC_H; ++hh)
            oacc = fmaf(hs[rq][hh], Wd2[(size_t)hh * DEC_O + o], oacc);
        out[(size_t)(r0 + rq) * DEC_O + o] = oacc;
    }
}

extern "C" void kernel_launch(void* const* d_in, const int* in_sizes, int n_in,
                              void* d_out, int out_size, void* d_ws, size_t ws_size,
                              hipStream_t stream)
{
    const float* x   = (const float*)d_in[0];
    const float* Wk  = (const float*)d_in[1];
    const float* bk  = (const float*)d_in[2];
    const float* Wq  = (const float*)d_in[3];
    const float* bq  = (const float*)d_in[4];
    const float* Wv  = (const float*)d_in[5];
    const float* bv  = (const float*)d_in[6];
    const float* Wa1 = (const float*)d_in[7];
    const float* ba1 = (const float*)d_in[8];
    const float* Wa2 = (const float*)d_in[9];
    const float* ba2 = (const float*)d_in[10];
    const float* Wd1 = (const float*)d_in[11];
    const float* bd1 = (const float*)d_in[12];
    const float* Wd2 = (const float*)d_in[13];
    const float* bd2 = (const float*)d_in[14];
    float* out = (float*)d_out;

    float* ws = (float*)d_ws;
    float* kBuf  = ws;                                   // B*N*D
    float* qBuf  = kBuf + (size_t)B * N * D;             // B*N*D
    float* hkBuf = qBuf + (size_t)B * N * D;             // B*NH*N*32
    float* hqBuf = hkBuf + (size_t)B * NH * N * 32;      // B*NH*N*32
    float* cBuf  = hqBuf + (size_t)B * NH * N * 32;      // B*N*C_DIM
    float* pBuf  = cBuf + (size_t)B * N * C_DIM;         // 1024*32*128 floats

    qkv_kernel<<<B * N / 4, 384, 0, stream>>>(x, Wk, bk, Wq, bq, Wv, bv, kBuf, qBuf, cBuf);
    hkq_kernel<<<B * N, 256, 0, stream>>>(kBuf, qBuf, Wa1, ba1, hkBuf, hqBuf);
    attn_kernel<<<B * NH * (N / TI) * SPLIT, 256, 0, stream>>>(hkBuf, hqBuf, Wa2, ba2, cBuf, pBuf);
    reduce_kernel<<<B * NH * (N / TI) * TI * D / 4 / 256, 256, 0, stream>>>(pBuf, cBuf);
    dec_kernel<<<B * N / 4, 512, 0, stream>>>(cBuf, Wd1, bd1, Wd2, bd2, out);
}

// Round 6
// 72.628 us; speedup vs baseline: 1.7627x; 1.3029x over previous
//
#include <hip/hip_runtime.h>
#include <hip/hip_bf16.h>
#include <math.h>

#define B 2
#define N 1024
#define D 128
#define DA 32
#define NH 4
#define AH 32
#define DEC_H 256
#define DEC_O 128
#define C_DIM ((NH + 1) * D)   // 640
#define TI 32
#define TJ 32
#define SPLIT 4                // j-dimension split for occupancy
#define JCHUNK (N / SPLIT)     // 256

typedef __attribute__((ext_vector_type(8))) short bf16x8;
typedef __attribute__((ext_vector_type(4))) float f32x4;
typedef __attribute__((ext_vector_type(4))) unsigned u32x4;

// round-to-nearest-even f32 -> bf16
static __device__ __forceinline__ unsigned pack2bf(float a, float b) {
    unsigned ua = __float_as_uint(a), ub = __float_as_uint(b);
    unsigned ra = (ua + 0x7FFFu + ((ua >> 16) & 1u)) >> 16;
    unsigned rb = (ub + 0x7FFFu + ((ub >> 16) & 1u)) >> 16;
    return (ra & 0xFFFFu) | (rb << 16);
}
static __device__ __forceinline__ unsigned short tobf(float a) {
    unsigned ua = __float_as_uint(a);
    return (unsigned short)((ua + 0x7FFFu + ((ua >> 16) & 1u)) >> 16);
}

// A-tiled bf16 index for a [rows][640-or-256 cols] matrix tiled [mm][kk][16][32]
// (KT = number of 32-wide k-tiles per row block)
static __device__ __forceinline__ int atile_idx(int row, int col, int KT) {
    return ((row >> 4) * KT + (col >> 5)) * 512 + (row & 15) * 32 + (col & 31);
}

// ---------------- kernel 1: k, q, v projections ----------------
// grid B*N/4 = 512 blocks x 384 threads; 4 rows per block.
// v written to vBuf (f32, stride D, for attn) and cbfT (bf16 A-tiled, for dec1).
__global__ __launch_bounds__(384) void qkv_kernel(
    const float* __restrict__ x,
    const float* __restrict__ Wk, const float* __restrict__ bk,
    const float* __restrict__ Wq, const float* __restrict__ bq,
    const float* __restrict__ Wv, const float* __restrict__ bv,
    float* __restrict__ kOut, float* __restrict__ qOut,
    float* __restrict__ vBuf, unsigned short* __restrict__ cbfT)
{
    const int t = threadIdx.x;
    const int row0 = blockIdx.x * 4;
    __shared__ float xs[4][D];
    for (int idx = t; idx < 4 * D; idx += 384)
        xs[idx >> 7][idx & 127] = x[(size_t)row0 * D + idx];
    __syncthreads();

    const int mat = t >> 7;      // 0,1,2 (wave-uniform)
    const int col = t & 127;
    const float* W = (mat == 0) ? Wk : (mat == 1) ? Wq : Wv;
    const float bias = (mat == 0) ? bk[col] : (mat == 1) ? bq[col] : bv[col];

    float a[4];
    #pragma unroll
    for (int m = 0; m < 4; ++m) a[m] = bias;
    for (int d = 0; d < D; ++d) {
        const float w = W[d * D + col];
        #pragma unroll
        for (int m = 0; m < 4; ++m) a[m] = fmaf(xs[m][d], w, a[m]);
    }
    if (mat == 0) {
        #pragma unroll
        for (int m = 0; m < 4; ++m) kOut[(size_t)(row0 + m) * D + col] = a[m];
    } else if (mat == 1) {
        #pragma unroll
        for (int m = 0; m < 4; ++m) qOut[(size_t)(row0 + m) * D + col] = a[m];
    } else {
        #pragma unroll
        for (int m = 0; m < 4; ++m) {
            const int grow = row0 + m;
            vBuf[(size_t)grow * D + col] = a[m];
            cbfT[atile_idx(grow, col, 20)] = tobf(a[m]);
        }
    }
}

// ---------------- kernel 2: hk = ki@Wa1_k ; hq = qi@Wa1_q + ba1 ----------------
__global__ __launch_bounds__(256) void hkq_kernel(
    const float* __restrict__ kIn, const float* __restrict__ qIn,
    const float* __restrict__ Wa1, const float* __restrict__ ba1,
    float* __restrict__ hkOut, float* __restrict__ hqOut)
{
    const int row = blockIdx.x;   // b*N + n
    const int t = threadIdx.x;    // 0..255
    __shared__ float ks[D], qs[D];
    if (t < D) ks[t] = kIn[(size_t)row * D + t];
    else       qs[t - D] = qIn[(size_t)row * D + (t - D)];
    __syncthreads();

    const bool isq = t >= 128;
    const int tt = t & 127;
    const int head = tt >> 5;   // 0..3
    const int a = tt & 31;      // 0..31
    const float* src = isq ? qs : ks;
    const float* W = Wa1 + (isq ? DA * AH : 0);
    float acc = isq ? ba1[a] : 0.f;
    #pragma unroll
    for (int c = 0; c < DA; ++c)
        acc = fmaf(src[head * DA + c], W[c * AH + a], acc);

    const int b = row >> 10, n = row & (N - 1);
    float* dst = isq ? hqOut : hkOut;
    dst[(((size_t)(b * NH + head)) * N + n) * 32 + a] = acc;
}

// ---------------- kernel 2b: transpose+tile decoder weights to bf16 ----------------
// wd1t[kk][n][32] from Wd1[640][256]; wd2t[kk][n][32] from Wd2[256][128].
__global__ __launch_bounds__(256) void wtrans_kernel(
    const float* __restrict__ Wd1, const float* __restrict__ Wd2,
    unsigned short* __restrict__ wd1t, unsigned short* __restrict__ wd2t)
{
    const int bid = blockIdx.x, t = threadIdx.x;
    if (bid < 640) {
        const int d = bid;
        wd1t[(d >> 5) * 8192 + t * 32 + (d & 31)] = tobf(Wd1[(size_t)d * 256 + t]);
    } else {
        const int d = bid - 640;
        if (t < 128)
            wd2t[(d >> 5) * 4096 + t * 32 + (d & 31)] = tobf(Wd2[(size_t)d * 128 + t]);
    }
}

// ---------------- kernel 3: attention ----------------
// grid = B*NH*(N/TI)*SPLIT = 1024 blocks x 256 threads. (unchanged from R5
// except v reads from compact vBuf, stride D)
__global__ __launch_bounds__(256, 4) void attn_kernel(
    const float* __restrict__ hk, const float* __restrict__ hq,
    const float* __restrict__ Wa2, const float* __restrict__ ba2,
    const float* __restrict__ vBuf, float* __restrict__ pBuf)
{
    const int t = threadIdx.x;
    const int sc = blockIdx.x & (SPLIT - 1);
    const int tile = (blockIdx.x >> 2) & 31;
    const int bh = blockIdx.x >> 7;     // b*NH + h
    const int b = bh >> 2;
    const int i0 = tile * TI;

    __shared__ float hqs[TJ][36];        // 144B rows (16B aligned)
    __shared__ unsigned wbf[TI][20];     // bf16 w[i][j]: 80B rows

    const float ba2v = ba2[0];

    // score mapping: rows (ti2, ti2+1), cols (tjA, tjA+16)
    const int ti2 = (t >> 4) << 1;
    const int tjA = t & 15;

    // hk rows in registers (block-invariant across the j-loop)
    float4 hkr0[8], hkr1[8];
    {
        const float4* s0 = reinterpret_cast<const float4*>(hk + ((size_t)bh * N + i0 + ti2) * 32);
        const float4* s1 = reinterpret_cast<const float4*>(hk + ((size_t)bh * N + i0 + ti2 + 1) * 32);
        #pragma unroll
        for (int a4 = 0; a4 < 8; ++a4) { hkr0[a4] = s0[a4]; hkr1[a4] = s1[a4]; }
    }

    // mfma mapping
    const int lane = t & 63;
    const int wv = t >> 6;               // wave id: d-tiles {2wv, 2wv+1}
    const int lm = lane & 15;
    const int lg = lane >> 4;

    f32x4 acc00 = {0.f, 0.f, 0.f, 0.f};
    f32x4 acc01 = {0.f, 0.f, 0.f, 0.f};
    f32x4 acc10 = {0.f, 0.f, 0.f, 0.f};
    f32x4 acc11 = {0.f, 0.f, 0.f, 0.f};

    const int d0 = (2 * wv) * 16 + lm;   // B-frag columns
    const int d1 = d0 + 16;

    const int jbeg = sc * JCHUNK, jend = jbeg + JCHUNK;
    for (int j0 = jbeg; j0 < jend; j0 += TJ) {
        // stage hq tile (coalesced)
        {
            const float* src = hq + ((size_t)bh * N + j0) * 32;
            for (int idx = t; idx < TJ * 32; idx += 256)
                hqs[idx >> 5][idx & 31] = src[idx];
        }
        // issue v fragment loads (global, coalesced)
        float v0[8], v1[8];
        {
            const float* vb = vBuf + (size_t)(b * N + j0 + 8 * lg) * D;
            #pragma unroll
            for (int e = 0; e < 8; ++e) {
                v0[e] = vb[(size_t)e * D + d0];
                v1[e] = vb[(size_t)e * D + d1];
            }
        }
        __syncthreads();   // SYNC_A: hqs ready; prev-iter wbf reads done

        {   // scores: 2x2 per thread (rows ti2/ti2+1, cols tjA/tjA+16)
            float sAA = ba2v, sAB = ba2v, sBA = ba2v, sBB = ba2v;
            #pragma unroll
            for (int a4 = 0; a4 < 8; ++a4) {
                const float4 qA = *reinterpret_cast<const float4*>(&hqs[tjA][a4 * 4]);
                const float4 qB = *reinterpret_cast<const float4*>(&hqs[tjA + 16][a4 * 4]);
                const float4 kA = hkr0[a4];
                const float4 kB = hkr1[a4];
                const float4 w4 = reinterpret_cast<const float4*>(Wa2)[a4];
                sAA += w4.x * fmaxf(kA.x + qA.x, 0.f) + w4.y * fmaxf(kA.y + qA.y, 0.f)
                     + w4.z * fmaxf(kA.z + qA.z, 0.f) + w4.w * fmaxf(kA.w + qA.w, 0.f);
                sAB += w4.x * fmaxf(kA.x + qB.x, 0.f) + w4.y * fmaxf(kA.y + qB.y, 0.f)
                     + w4.z * fmaxf(kA.z + qB.z, 0.f) + w4.w * fmaxf(kA.w + qB.w, 0.f);
                sBA += w4.x * fmaxf(kB.x + qA.x, 0.f) + w4.y * fmaxf(kB.y + qA.y, 0.f)
                     + w4.z * fmaxf(kB.z + qA.z, 0.f) + w4.w * fmaxf(kB.w + qA.w, 0.f);
                sBB += w4.x * fmaxf(kB.x + qB.x, 0.f) + w4.y * fmaxf(kB.y + qB.y, 0.f)
                     + w4.z * fmaxf(kB.z + qB.z, 0.f) + w4.w * fmaxf(kB.w + qB.w, 0.f);
            }
            const int giA = i0 + ti2, giB = giA + 1;
            const int gjA = j0 + tjA, gjB = gjA + 16;
            if (giA == gjA) sAA -= 10000.f;
            if (giA == gjB) sAB -= 10000.f;
            if (giB == gjA) sBA -= 10000.f;
            if (giB == gjB) sBB -= 10000.f;
            const float wAA = 1.f / (1.f + __expf(-sAA));
            const float wAB = 1.f / (1.f + __expf(-sAB));
            const float wBA = 1.f / (1.f + __expf(-sBA));
            const float wBB = 1.f / (1.f + __expf(-sBB));
            unsigned short* wb = reinterpret_cast<unsigned short*>(&wbf[0][0]);
            wb[ti2 * 40 + tjA]            = tobf(wAA);
            wb[ti2 * 40 + tjA + 16]       = tobf(wAB);
            wb[(ti2 + 1) * 40 + tjA]      = tobf(wBA);
            wb[(ti2 + 1) * 40 + tjA + 16] = tobf(wBB);
        }

        // pack v fragments to bf16 (waits on the early global loads)
        u32x4 pb0, pb1;
        pb0.x = pack2bf(v0[0], v0[1]); pb0.y = pack2bf(v0[2], v0[3]);
        pb0.z = pack2bf(v0[4], v0[5]); pb0.w = pack2bf(v0[6], v0[7]);
        pb1.x = pack2bf(v1[0], v1[1]); pb1.y = pack2bf(v1[2], v1[3]);
        pb1.z = pack2bf(v1[4], v1[5]); pb1.w = pack2bf(v1[6], v1[7]);
        const bf16x8 b0 = __builtin_bit_cast(bf16x8, pb0);
        const bf16x8 b1 = __builtin_bit_cast(bf16x8, pb1);

        __syncthreads();   // SYNC_B: wbf ready

        {   // PV: 4x mfma per wave
            const char* wbase = reinterpret_cast<const char*>(&wbf[0][0]);
            const bf16x8 a0 = *reinterpret_cast<const bf16x8*>(wbase + lm * 80 + lg * 16);
            const bf16x8 a1 = *reinterpret_cast<const bf16x8*>(wbase + (16 + lm) * 80 + lg * 16);
            acc00 = __builtin_amdgcn_mfma_f32_16x16x32_bf16(a0, b0, acc00, 0, 0, 0);
            acc01 = __builtin_amdgcn_mfma_f32_16x16x32_bf16(a0, b1, acc01, 0, 0, 0);
            acc10 = __builtin_amdgcn_mfma_f32_16x16x32_bf16(a1, b0, acc10, 0, 0, 0);
            acc11 = __builtin_amdgcn_mfma_f32_16x16x32_bf16(a1, b1, acc11, 0, 0, 0);
        }
    }

    // write 32x128 partial tile to pBuf[blockIdx.x] (D-frag: col=lane&15, row=4*lg+r)
    float* dst = pBuf + (size_t)blockIdx.x * (TI * D);
    #pragma unroll
    for (int r = 0; r < 4; ++r) {
        const int ia = lg * 4 + r;
        dst[ia * D + d0]        = acc00[r];
        dst[ia * D + d1]        = acc01[r];
        dst[(16 + ia) * D + d0] = acc10[r];
        dst[(16 + ia) * D + d1] = acc11[r];
    }
}

// ---------------- kernel 3b: reduce SPLIT partials -> cbfT (bf16 A-tiled) ----------------
__global__ __launch_bounds__(256) void reduce_kernel(
    const float* __restrict__ pBuf, unsigned short* __restrict__ cbfT)
{
    const int e4 = blockIdx.x * 256 + threadIdx.x;   // 0 .. 262143
    const int d4 = e4 & 31;
    const int i = (e4 >> 5) & 31;
    const int tile = (e4 >> 10) & 31;
    const int bh = e4 >> 15;
    const float4* p = reinterpret_cast<const float4*>(pBuf);
    const size_t base = ((size_t)(bh * 32 + tile) * SPLIT) * (TI * D / 4) + i * (D / 4) + d4;
    float4 s = p[base];
    #pragma unroll
    for (int sc = 1; sc < SPLIT; ++sc) {
        const float4 q = p[base + (size_t)sc * (TI * D / 4)];
        s.x += q.x; s.y += q.y; s.z += q.z; s.w += q.w;
    }
    const int b = bh >> 2, h = bh & 3;
    const int grow = b * N + tile * 32 + i;
    const int col0 = (h + 1) * 128 + 4 * d4;
    uint2 pk;
    pk.x = pack2bf(s.x, s.y);
    pk.y = pack2bf(s.z, s.w);
    *reinterpret_cast<uint2*>(cbfT + atile_idx(grow, col0, 20)) = pk;
}

// ---------------- kernel 4a: decoder layer 1 (bf16 MFMA, no LDS, no barriers) ----------------
// 1024 waves: wave = 16 rows x 32 cols. grid 256 blocks x 256 threads.
__global__ __launch_bounds__(256) void dec1_kernel(
    const unsigned short* __restrict__ cbfT, const unsigned short* __restrict__ wd1t,
    const float* __restrict__ bd1, unsigned short* __restrict__ hbfT)
{
    const int t = threadIdx.x;
    const int lane = t & 63, lm = lane & 15, lg = lane >> 4;
    const int wid = blockIdx.x * 4 + (t >> 6);
    const int mm = wid >> 3;         // 0..127 (row block)
    const int ng = wid & 7;          // 0..7   (32-col group)

    f32x4 acc0 = {0.f, 0.f, 0.f, 0.f}, acc1 = {0.f, 0.f, 0.f, 0.f};
    const int abase = mm * 20 * 512 + lm * 32 + lg * 8;
    const int bbase = lm * 32 + lg * 8;
    #pragma unroll 4
    for (int kk = 0; kk < 20; ++kk) {
        const bf16x8 a  = *reinterpret_cast<const bf16x8*>(cbfT + abase + kk * 512);
        const bf16x8 b0 = *reinterpret_cast<const bf16x8*>(wd1t + kk * 8192 + (2 * ng) * 512 + bbase);
        const bf16x8 b1 = *reinterpret_cast<const bf16x8*>(wd1t + kk * 8192 + (2 * ng + 1) * 512 + bbase);
        acc0 = __builtin_amdgcn_mfma_f32_16x16x32_bf16(a, b0, acc0, 0, 0, 0);
        acc1 = __builtin_amdgcn_mfma_f32_16x16x32_bf16(a, b1, acc1, 0, 0, 0);
    }
    // bias + relu -> bf16, stored A-tiled: wave's cols = one 32-wide k-tile (ng)
    const float bias0 = bd1[ng * 32 + lm];
    const float bias1 = bd1[ng * 32 + 16 + lm];
    unsigned short* hb = hbfT + (mm * 8 + ng) * 512;
    #pragma unroll
    for (int r = 0; r < 4; ++r) {
        const int irow = lg * 4 + r;
        hb[irow * 32 + lm]      = tobf(fmaxf(acc0[r] + bias0, 0.f));
        hb[irow * 32 + 16 + lm] = tobf(fmaxf(acc1[r] + bias1, 0.f));
    }
}

// ---------------- kernel 4b: decoder layer 2 ----------------
// 512 waves: wave = 16 rows x 32 cols. grid 128 blocks x 256 threads.
__global__ __launch_bounds__(256) void dec2_kernel(
    const unsigned short* __restrict__ hbfT, const unsigned short* __restrict__ wd2t,
    const float* __restrict__ bd2, float* __restrict__ out)
{
    const int t = threadIdx.x;
    const int lane = t & 63, lm = lane & 15, lg = lane >> 4;
    const int wid = blockIdx.x * 4 + (t >> 6);   // 0..511
    const int mm = wid >> 2;   // 0..127
    const int og = wid & 3;    // 0..3

    f32x4 acc0 = {0.f, 0.f, 0.f, 0.f}, acc1 = {0.f, 0.f, 0.f, 0.f};
    const int bbase = lm * 32 + lg * 8;
    #pragma unroll
    for (int kk = 0; kk < 8; ++kk) {
        const bf16x8 a  = *reinterpret_cast<const bf16x8*>(hbfT + (mm * 8 + kk) * 512 + bbase);
        const bf16x8 b0 = *reinterpret_cast<const bf16x8*>(wd2t + kk * 4096 + (2 * og) * 512 + bbase);
        const bf16x8 b1 = *reinterpret_cast<const bf16x8*>(wd2t + kk * 4096 + (2 * og + 1) * 512 + bbase);
        acc0 = __builtin_amdgcn_mfma_f32_16x16x32_bf16(a, b0, acc0, 0, 0, 0);
        acc1 = __builtin_amdgcn_mfma_f32_16x16x32_bf16(a, b1, acc1, 0, 0, 0);
    }
    const float bias0 = bd2[og * 32 + lm];
    const float bias1 = bd2[og * 32 + 16 + lm];
    float* op = out + (size_t)(mm * 16) * DEC_O;
    #pragma unroll
    for (int r = 0; r < 4; ++r) {
        const int irow = lg * 4 + r;
        op[irow * DEC_O + og * 32 + lm]      = acc0[r] + bias0;
        op[irow * DEC_O + og * 32 + 16 + lm] = acc1[r] + bias1;
    }
}

extern "C" void kernel_launch(void* const* d_in, const int* in_sizes, int n_in,
                              void* d_out, int out_size, void* d_ws, size_t ws_size,
                              hipStream_t stream)
{
    const float* x   = (const float*)d_in[0];
    const float* Wk  = (const float*)d_in[1];
    const float* bk  = (const float*)d_in[2];
    const float* Wq  = (const float*)d_in[3];
    const float* bq  = (const float*)d_in[4];
    const float* Wv  = (const float*)d_in[5];
    const float* bv  = (const float*)d_in[6];
    const float* Wa1 = (const float*)d_in[7];
    const float* ba1 = (const float*)d_in[8];
    const float* Wa2 = (const float*)d_in[9];
    const float* ba2 = (const float*)d_in[10];
    const float* Wd1 = (const float*)d_in[11];
    const float* bd1 = (const float*)d_in[12];
    const float* Wd2 = (const float*)d_in[13];
    const float* bd2 = (const float*)d_in[14];
    float* out = (float*)d_out;

    float* ws = (float*)d_ws;
    float* kBuf  = ws;                       // 262144
    float* qBuf  = kBuf + 262144;
    float* hkBuf = qBuf + 262144;
    float* hqBuf = hkBuf + 262144;
    float* vBuf  = hqBuf + 262144;           // B*N*D f32
    float* pBuf  = vBuf + 262144;            // 1024*32*128 f32
    unsigned short* cbfT = (unsigned short*)(pBuf + 4194304);  // 2048*640 bf16 (A-tiled)
    unsigned short* hbfT = cbfT + 1310720;                     // 2048*256 bf16 (A-tiled)
    unsigned short* wd1t = hbfT + 524288;                      // 20*256*32
    unsigned short* wd2t = wd1t + 163840;                      // 8*128*32

    qkv_kernel<<<B * N / 4, 384, 0, stream>>>(x, Wk, bk, Wq, bq, Wv, bv, kBuf, qBuf, vBuf, cbfT);
    hkq_kernel<<<B * N, 256, 0, stream>>>(kBuf, qBuf, Wa1, ba1, hkBuf, hqBuf);
    wtrans_kernel<<<896, 256, 0, stream>>>(Wd1, Wd2, wd1t, wd2t);
    attn_kernel<<<B * NH * (N / TI) * SPLIT, 256, 0, stream>>>(hkBuf, hqBuf, Wa2, ba2, vBuf, pBuf);
    reduce_kernel<<<1024, 256, 0, stream>>>(pBuf, cbfT);
    dec1_kernel<<<256, 256, 0, stream>>>(cbfT, wd1t, bd1, hbfT);
    dec2_kernel<<<128, 256, 0, stream>>>(hbfT, wd2t, bd2, out);
}